// Round 7
// baseline (3220.099 us; speedup 1.0000x reference)
//
#include <hip/hip_runtime.h>
#include <stdint.h>

// LSTM: B=32, S=1024, I=H=512, 4H=2048
// Phase 1: x_gates = x @ W_ih^T + (b_ih + b_hh)   [bf16 MFMA GEMM]
// Phase 2: persistent cooperative kernel, 8 groups x 32 WGs x 512 threads,
//   XCD-swizzled (g=blockIdx&7) — r6 confirmed: FETCH 531->115MB, conflicts 0.
//   r7: the step cost is LDS RETURN BW — old layout read 1KB/thread/step
//   (64 ds_read_b128, 1 FMA per float read) = 512KB/WG/step ~ 6100cyc at
//   85B/cyc. Fix: row-blocking. Thread (kc=tid>>4, rg=tid&15) owns 4 rows x
//   16k -> each h f32x4 feeds 16 FMAs; LDS reads/thread drop 64->16.
//   Reduce: 32 chunks summed by 256 threads; the 4 gate values per (h,b)
//   land in lanes jj/jj+16/jj+32/jj+48 of one wave -> __shfl gather (no
//   gates_lds pass). Sync skeleton byte-identical to r6.

typedef __attribute__((ext_vector_type(8))) short bf16x8;
typedef __attribute__((ext_vector_type(4))) float f32x4;

__device__ __forceinline__ unsigned short f2bf(float f) {
  union { float f; unsigned u; } v; v.f = f;
  unsigned r = (v.u + 0x7fffu + ((v.u >> 16) & 1u)) >> 16;  // RNE
  return (unsigned short)r;
}
__device__ __forceinline__ float bf2f(unsigned short h) {
  union { unsigned u; float f; } v; v.u = ((unsigned)h) << 16;
  return v.f;
}

__global__ __launch_bounds__(256) void cvt_bf16(const float* __restrict__ in,
                                                unsigned short* __restrict__ out, int n) {
  int i = (blockIdx.x * 256 + threadIdx.x) * 4;
  if (i >= n) return;
  float4 v = *(const float4*)(in + i);
  ushort4 o;
  o.x = f2bf(v.x); o.y = f2bf(v.y); o.z = f2bf(v.z); o.w = f2bf(v.w);
  *(ushort4*)(out + i) = o;
}

// C[m][n] = sum_k A[m][k]*B[n][k] + b_ih[n] + b_hh[n], stored bf16.
__global__ __launch_bounds__(256) void gemm_xg(const unsigned short* __restrict__ A,
                                               const unsigned short* __restrict__ Bw,
                                               const float* __restrict__ b_ih,
                                               const float* __restrict__ b_hh,
                                               unsigned short* __restrict__ xg) {
  __shared__ unsigned short Asub[128][32];
  __shared__ unsigned short Bsub[128][32];
  const int tid = threadIdx.x;
  const int mb = blockIdx.x >> 4;
  const int nb = blockIdx.x & 15;
  const int wv = tid >> 6, ln = tid & 63;
  const int wr = wv >> 1, wc = wv & 1;
  const int lrow = tid >> 1;
  const int lseg = (tid & 1) * 16;

  const unsigned short* Ag = A + (size_t)(mb * 128 + lrow) * 512 + lseg;
  const unsigned short* Bg = Bw + (size_t)(nb * 128 + lrow) * 512 + lseg;

  f32x4 acc[4][4] = {};
  const int frow = ln & 15;
  const int kq = (ln >> 4) * 8;

  for (int k0 = 0; k0 < 512; k0 += 32) {
    uint4 a0 = *(const uint4*)(Ag + k0);
    uint4 a1 = *(const uint4*)(Ag + k0 + 8);
    uint4 b0 = *(const uint4*)(Bg + k0);
    uint4 b1 = *(const uint4*)(Bg + k0 + 8);
    __syncthreads();
    *(uint4*)&Asub[lrow][lseg]     = a0;
    *(uint4*)&Asub[lrow][lseg + 8] = a1;
    *(uint4*)&Bsub[lrow][lseg]     = b0;
    *(uint4*)&Bsub[lrow][lseg + 8] = b1;
    __syncthreads();
    bf16x8 af[4], bfr[4];
#pragma unroll
    for (int mi = 0; mi < 4; ++mi)
      af[mi] = *(const bf16x8*)&Asub[wr * 64 + mi * 16 + frow][kq];
#pragma unroll
    for (int ni = 0; ni < 4; ++ni)
      bfr[ni] = *(const bf16x8*)&Bsub[wc * 64 + ni * 16 + frow][kq];
#pragma unroll
    for (int mi = 0; mi < 4; ++mi)
#pragma unroll
      for (int ni = 0; ni < 4; ++ni)
        acc[mi][ni] = __builtin_amdgcn_mfma_f32_16x16x32_bf16(af[mi], bfr[ni], acc[mi][ni], 0, 0, 0);
  }

  const int col0 = nb * 128 + wc * 64 + frow;
  float bias[4];
#pragma unroll
  for (int ni = 0; ni < 4; ++ni)
    bias[ni] = b_ih[col0 + ni * 16] + b_hh[col0 + ni * 16];

#pragma unroll
  for (int mi = 0; mi < 4; ++mi) {
    const int m0 = mb * 128 + wr * 64 + mi * 16 + (ln >> 4) * 4;
#pragma unroll
    for (int ni = 0; ni < 4; ++ni) {
#pragma unroll
      for (int rr = 0; rr < 4; ++rr) {
        float v = acc[mi][ni][rr] + bias[ni];
        xg[(size_t)(m0 + rr) * 2048 + col0 + ni * 16] = f2bf(v);
      }
    }
  }
}

// 16 FMAs: one gate-row's 16-wide dot-product chunk into accumulator A.
#define ROW_FMA(A, W0v, W1v, W2v, W3v)                                        \
  A = fmaf(W0v.x, hv0.x, A); A = fmaf(W0v.y, hv0.y, A);                       \
  A = fmaf(W0v.z, hv0.z, A); A = fmaf(W0v.w, hv0.w, A);                       \
  A = fmaf(W1v.x, hv1.x, A); A = fmaf(W1v.y, hv1.y, A);                       \
  A = fmaf(W1v.z, hv1.z, A); A = fmaf(W1v.w, hv1.w, A);                       \
  A = fmaf(W2v.x, hv2.x, A); A = fmaf(W2v.y, hv2.y, A);                       \
  A = fmaf(W2v.z, hv2.z, A); A = fmaf(W2v.w, hv2.w, A);                       \
  A = fmaf(W3v.x, hv3.x, A); A = fmaf(W3v.y, hv3.y, A);                       \
  A = fmaf(W3v.z, hv3.z, A); A = fmaf(W3v.w, hv3.w, A)

// One batch: 4 h-vector loads (16 floats) feed 4 rows x 16 FMAs.
#define FMA_BATCH(b)                                                          \
  do {                                                                        \
    f32x4 hv0 = *(const f32x4*)&h_lds[(b) * 512 + kcb16];                     \
    f32x4 hv1 = *(const f32x4*)&h_lds[(b) * 512 + kcb16 + 4];                 \
    f32x4 hv2 = *(const f32x4*)&h_lds[(b) * 512 + kcb16 + 8];                 \
    f32x4 hv3 = *(const f32x4*)&h_lds[(b) * 512 + kcb16 + 12];                \
    ROW_FMA(acc[0][b], Wr0_0, Wr0_1, Wr0_2, Wr0_3);                           \
    ROW_FMA(acc[1][b], Wr1_0, Wr1_1, Wr1_2, Wr1_3);                           \
    ROW_FMA(acc[2][b], Wr2_0, Wr2_1, Wr2_2, Wr2_3);                           \
    ROW_FMA(acc[3][b], Wr3_0, Wr3_1, Wr3_2, Wr3_3);                           \
  } while (0)

// Persistent recurrent kernel. Grid = 256 WGs (8 groups x 32), 512 threads.
// XCD-swizzled: g = blockIdx&7, w = blockIdx>>3 owns h-indices [16w,16w+16)
// -> 64 gate-rows. Thread (kc=tid>>4 in [0,32), rg=tid&15) owns gate-rows
// [4rg,4rg+4) x k-chunk [16kc,16kc+16): W = 4x16 floats in 16 named f32x4.
__global__ __launch_bounds__(512, 1) void lstm_rec(const unsigned short* __restrict__ xg,
                                                   const float* __restrict__ W_hh,
                                                   const float* __restrict__ h0,
                                                   const float* __restrict__ c0,
                                                   float* __restrict__ out,
                                                   float* __restrict__ hn,
                                                   float* __restrict__ cn,
                                                   float* h_buf,        // [2][32][512]
                                                   unsigned int* cnt) { // [8], stride 64 uints
  __shared__ float h_lds[2048];
  __shared__ float scratch[8704];      // [batch(4)@2176][kc(32)@68][row(64)]
  __shared__ float c_lds[64];

  const int tid = threadIdx.x;   // 0..511
  const int g = blockIdx.x & 7;  // XCD swizzle: group g on XCD g
  const int w = blockIdx.x >> 3; // 0..31
  const int gb0 = g * 4;
  const int kc = tid >> 4;       // 0..31: 16-wide k-chunk
  const int rg = tid & 15;       // row-group: rows [4rg, 4rg+4)
  const int kcb16 = kc * 16;
  unsigned int* my_cnt = cnt + g * 64;  // 256B stride: no false sharing

  // W_hh rows for this thread: 4 consecutive gate-rows.
  // row r = 4rg+ri -> grow = (rg>>2)*512 + w*16 + (rg&3)*4 + ri.
  const int grow0 = (rg >> 2) * 512 + w * 16 + (rg & 3) * 4;
  const float* wp0 = W_hh + (size_t)(grow0 + 0) * 512 + kcb16;
  const float* wp1 = W_hh + (size_t)(grow0 + 1) * 512 + kcb16;
  const float* wp2 = W_hh + (size_t)(grow0 + 2) * 512 + kcb16;
  const float* wp3 = W_hh + (size_t)(grow0 + 3) * 512 + kcb16;
  f32x4 Wr0_0 = *(const f32x4*)(wp0), Wr0_1 = *(const f32x4*)(wp0 + 4),
        Wr0_2 = *(const f32x4*)(wp0 + 8), Wr0_3 = *(const f32x4*)(wp0 + 12);
  f32x4 Wr1_0 = *(const f32x4*)(wp1), Wr1_1 = *(const f32x4*)(wp1 + 4),
        Wr1_2 = *(const f32x4*)(wp1 + 8), Wr1_3 = *(const f32x4*)(wp1 + 12);
  f32x4 Wr2_0 = *(const f32x4*)(wp2), Wr2_1 = *(const f32x4*)(wp2 + 4),
        Wr2_2 = *(const f32x4*)(wp2 + 8), Wr2_3 = *(const f32x4*)(wp2 + 12);
  f32x4 Wr3_0 = *(const f32x4*)(wp3), Wr3_1 = *(const f32x4*)(wp3 + 4),
        Wr3_2 = *(const f32x4*)(wp3 + 8), Wr3_3 = *(const f32x4*)(wp3 + 12);
  asm volatile("" : "+v"(Wr0_0), "+v"(Wr0_1), "+v"(Wr0_2), "+v"(Wr0_3),
                    "+v"(Wr1_0), "+v"(Wr1_1), "+v"(Wr1_2), "+v"(Wr1_3),
                    "+v"(Wr2_0), "+v"(Wr2_1), "+v"(Wr2_2), "+v"(Wr2_3),
                    "+v"(Wr3_0), "+v"(Wr3_1), "+v"(Wr3_2), "+v"(Wr3_3));

  {
    *(float4*)&h_lds[tid * 4] = *(const float4*)(h0 + gb0 * 512 + tid * 4);
    if (tid < 64) {
      int jj = tid & 15, bb = tid >> 4;
      c_lds[bb * 16 + jj] = c0[(gb0 + bb) * 512 + w * 16 + jj];
    }
  }
  __syncthreads();

  // Reduce/gate-phase identity: wave b2 (0..3) handles batch b2; lane = row.
  const int lane = tid & 63;
  const int b2 = tid >> 6;
  const int jj = lane & 15;
  const int grow_r = (lane >> 4) * 512 + w * 16 + jj;

  for (int t = 0; t < 1024; ++t) {
    // Reduce-phase xg load issued at loop top -> latency hidden under FMA.
    float xg_v = 0.f;
    if (tid < 256)
      xg_v = bf2f(xg[(size_t)((gb0 + b2) * 1024 + t) * 2048 + grow_r]);

    float acc[4][4] = {};
    FMA_BATCH(0); FMA_BATCH(1); FMA_BATCH(2); FMA_BATCH(3);

    // scratch[b][kc][row]: thread's rows 4rg..4rg+3 are contiguous -> b128.
#pragma unroll
    for (int b = 0; b < 4; ++b) {
      f32x4 v;
      v.x = acc[0][b]; v.y = acc[1][b]; v.z = acc[2][b]; v.w = acc[3][b];
      *(f32x4*)&scratch[b * 2176 + kc * 68 + rg * 4] = v;
    }
    __syncthreads();  // scratch ready

    if (tid < 256) {
      // Sum 32 k-chunks for (row=lane, batch=b2); 4 partials for ILP.
      const float* sp = &scratch[b2 * 2176 + lane];
      float s0 = 0.f, s1 = 0.f, s2 = 0.f, s3 = 0.f;
#pragma unroll
      for (int q = 0; q < 32; q += 4) {
        s0 += sp[q * 68];
        s1 += sp[(q + 1) * 68];
        s2 += sp[(q + 2) * 68];
        s3 += sp[(q + 3) * 68];
      }
      float s = xg_v + ((s0 + s1) + (s2 + s3));
      // Gate gather within the wave: rows jj, 16+jj, 32+jj, 48+jj.
      float gi = __shfl(s, jj);
      float gf = __shfl(s, jj + 16);
      float gc = __shfl(s, jj + 32);
      float go = __shfl(s, jj + 48);
      if (lane < 16) {
        float ig = 1.f / (1.f + __expf(-gi));
        float fg = 1.f / (1.f + __expf(-gf));
        float gt = tanhf(gc);
        float og = 1.f / (1.f + __expf(-go));
        float c = fmaf(fg, c_lds[b2 * 16 + jj], ig * gt);
        c_lds[b2 * 16 + jj] = c;
        float hv = og * tanhf(c);
        out[(size_t)((gb0 + b2) * 1024 + t) * 512 + w * 16 + jj] = hv;
        __hip_atomic_store(&h_buf[((t + 1) & 1) * 16384 + (gb0 + b2) * 512 + w * 16 + jj], hv,
                           __ATOMIC_RELAXED, __HIP_MEMORY_SCOPE_AGENT);
        if (t == 1023) {
          hn[(gb0 + b2) * 512 + w * 16 + jj] = hv;
          cn[(gb0 + b2) * 512 + w * 16 + jj] = c;
        }
      }
    }
    __syncthreads();  // s_waitcnt vmcnt(0) before s_barrier: h stores are at LLC

    if (t < 1023) {
      if (tid == 0) {
        __hip_atomic_fetch_add(my_cnt, 1u, __ATOMIC_RELAXED, __HIP_MEMORY_SCOPE_AGENT);
        const unsigned target = 32u * (unsigned)(t + 1);
        while (__hip_atomic_load(my_cnt, __ATOMIC_RELAXED, __HIP_MEMORY_SCOPE_AGENT) < target)
          __builtin_amdgcn_s_sleep(2);
      }
      __syncthreads();
      // Stage next h into LDS; 8-byte relaxed atomic loads (2 VMEM ops/thread).
      const unsigned long long* hb =
          (const unsigned long long*)(h_buf + ((t + 1) & 1) * 16384 + gb0 * 512 + tid * 4);
      unsigned long long v0 = __hip_atomic_load(hb,     __ATOMIC_RELAXED, __HIP_MEMORY_SCOPE_AGENT);
      unsigned long long v1 = __hip_atomic_load(hb + 1, __ATOMIC_RELAXED, __HIP_MEMORY_SCOPE_AGENT);
      *(unsigned long long*)&h_lds[tid * 4]     = v0;
      *(unsigned long long*)&h_lds[tid * 4 + 2] = v1;
      __syncthreads();
    }
  }
}

extern "C" void kernel_launch(void* const* d_in, const int* in_sizes, int n_in,
                              void* d_out, int out_size, void* d_ws, size_t ws_size,
                              hipStream_t stream) {
  const float* x    = (const float*)d_in[0];
  const float* W_ih = (const float*)d_in[1];
  const float* W_hh = (const float*)d_in[2];
  const float* b_ih = (const float*)d_in[3];
  const float* b_hh = (const float*)d_in[4];
  const float* h0   = (const float*)d_in[5];
  const float* c0   = (const float*)d_in[6];
  float* out = (float*)d_out;
  float* hn = out + (size_t)32 * 1024 * 512;
  float* cn = hn + 32 * 512;

  uint8_t* ws = (uint8_t*)d_ws;
  unsigned short* xg   = (unsigned short*)ws;                   // 134,217,728 B
  unsigned short* x_bf = (unsigned short*)(ws + 134217728u);    //  33,554,432 B
  unsigned short* w_bf = (unsigned short*)(ws + 167772160u);    //   2,097,152 B
  float* h_buf         = (float*)(ws + 169869312u);             //     131,072 B
  unsigned int* cnt    = (unsigned int*)(ws + 170000384u);      //  8 * 256 B

  hipMemsetAsync(cnt, 0, 8 * 256, stream);
  cvt_bf16<<<dim3(16384), dim3(256), 0, stream>>>(x, x_bf, 16777216);
  cvt_bf16<<<dim3(1024), dim3(256), 0, stream>>>(W_ih, w_bf, 1048576);
  gemm_xg<<<dim3(4096), dim3(256), 0, stream>>>(x_bf, w_bf, b_ih, b_hh, xg);

  void* args[] = {(void*)&xg, (void*)&W_hh, (void*)&h0, (void*)&c0,
                  (void*)&out, (void*)&hn, (void*)&cn, (void*)&h_buf, (void*)&cnt};
  hipLaunchCooperativeKernel((const void*)lstm_rec, dim3(256), dim3(512), args, 0, stream);
}